// Round 1
// baseline (474.830 us; speedup 1.0000x reference)
//
#include <hip/hip_runtime.h>
#include <math.h>

#define HW 1024
#define Hd 32
#define Wd 32
#define Bn 8
#define Cc 256

// ---------------- Kernel A: primary caps (1x1 conv + BN + SiLU + squash) ----
// one wave per pixel; lane = output channel (64). child stored [pix][64].
__global__ __launch_bounds__(256) void kA(const float* __restrict__ x,
        const float* __restrict__ pw, const float* __restrict__ gamma,
        const float* __restrict__ beta, const float* __restrict__ mean,
        const float* __restrict__ var, float* __restrict__ child_t) {
    __shared__ float xs[4][256];
    int wid = threadIdx.x >> 6;
    int lane = threadIdx.x & 63;
    int m = blockIdx.x * 4 + wid;           // pixel 0..8191
    int b = m >> 10, hw = m & 1023;
    const float* xp = x + (size_t)b * Cc * HW + hw;
    #pragma unroll
    for (int k = 0; k < 4; ++k)
        xs[wid][lane + 64 * k] = xp[(size_t)(lane + 64 * k) * HW];
    __syncthreads();
    int o = lane;
    double acc = 0.0;
    const float4* w4 = reinterpret_cast<const float4*>(pw + o * 256);
    #pragma unroll 16
    for (int c4 = 0; c4 < 64; ++c4) {
        float4 wv = w4[c4];
        acc += (double)wv.x * (double)xs[wid][c4 * 4 + 0];
        acc += (double)wv.y * (double)xs[wid][c4 * 4 + 1];
        acc += (double)wv.z * (double)xs[wid][c4 * 4 + 2];
        acc += (double)wv.w * (double)xs[wid][c4 * 4 + 3];
    }
    double t = (acc - (double)mean[o]) / sqrt((double)var[o] + 1e-5) *
               (double)gamma[o] + (double)beta[o];
    double s = t / (1.0 + exp(-t));              // SiLU
    double sq = s * s;                            // squash over 8-lane capsule
    sq += __shfl_xor(sq, 1);
    sq += __shfl_xor(sq, 2);
    sq += __shfl_xor(sq, 4);
    double f = (sq / (1.0 + sq)) / sqrt(sq + 1e-7);
    child_t[(size_t)m * 64 + o] = (float)(s * f);
}

// ---------------- Kernel B: 3x3 offset conv + tanh -> sampling grids --------
// thread per (pixel, out-channel oc in 0..7). grids stored [pix][4][2].
__global__ __launch_bounds__(256) void kB(const float* __restrict__ x,
        const float* __restrict__ ow, const float* __restrict__ ob,
        float* __restrict__ grids) {
    int g = blockIdx.x * 256 + threadIdx.x;   // 65536 threads
    int pix = g & 8191;
    int oc = g >> 13;
    int b = pix >> 10, hw = pix & 1023;
    int yy = hw >> 5, xx = hw & 31;
    const float* xb = x + (size_t)b * Cc * HW;
    const float* wb = ow + (size_t)oc * Cc * 9;
    double acc = 0.0;
    for (int c = 0; c < Cc; ++c) {
        const float* xc = xb + (size_t)c * HW;
        const float* wc = wb + c * 9;
        float s = 0.f;
        #pragma unroll
        for (int ky = 0; ky < 3; ++ky) {
            int yq = yy + ky - 1;
            if (yq < 0 || yq > Hd - 1) continue;
            #pragma unroll
            for (int kx = 0; kx < 3; ++kx) {
                int xq = xx + kx - 1;
                if (xq < 0 || xq > Wd - 1) continue;
                s += xc[yq * Wd + xq] * wc[ky * 3 + kx];
            }
        }
        acc += (double)s;
    }
    acc += (double)ob[oc];
    double t = tanh(acc);                     // OFFSET_SCALE = 1.0
    int coord = oc & 1, si = oc >> 1;
    double base = coord ? (-1.0 + 2.0 * (double)yy / 31.0)
                        : (-1.0 + 2.0 * (double)xx / 31.0);
    double gv = base + t / 15.5;              // scale = (dim-1)/2 = 15.5
    grids[(size_t)pix * 8 + si * 2 + coord] = (float)gv;
}

// ---------------- Kernel C: reorder routing_W for coalesced float4 reads ----
// lane l <-> (n = l>>1, half = l&1); chunk j = o_loc*128 + d*8 + i (512 floats)
// wt[j4*256 + l*4 + e] = W[n*1024 + half*512 + j4*4 + e]
__global__ void kC(const float* __restrict__ rw, float* __restrict__ wt) {
    int t = blockIdx.x * 256 + threadIdx.x;  // 32768
    int e = t & 3, l = (t >> 2) & 63, j4 = t >> 8;
    int n = l >> 1, half = l & 1;
    wt[t] = rw[n * 1024 + half * 512 + j4 * 4 + e];
}

// ---------------- Kernel D: bilinear sample + u_hat + dynamic routing -------
// one wave per pixel. lane <-> (n = lane>>1, half = lane&1).
// u_hat[n][half*4+o_loc][d] lives in regs u[4][16].
__global__ __launch_bounds__(256) void kD(const float* __restrict__ child_t,
        const float* __restrict__ grids, const float* __restrict__ wt,
        float* __restrict__ out) {
    int wid = threadIdx.x >> 6, lane = threadIdx.x & 63;
    int m = blockIdx.x * 4 + wid;             // pixel
    int b = m >> 10, hw = m & 1023;
    int n = lane >> 1, half = lane & 1;
    int si = n >> 3, ch = n & 7;

    // ---- bilinear sampling (align_corners=True, zeros padding) ----
    float gx = grids[m * 8 + si * 2 + 0];
    float gy = grids[m * 8 + si * 2 + 1];
    double xd = ((double)gx + 1.0) * 0.5 * 31.0;
    double yd = ((double)gy + 1.0) * 0.5 * 31.0;
    double x0 = floor(xd), y0 = floor(yd);
    double wx1 = xd - x0, wx0 = 1.0 - wx1;
    double wy1 = yd - y0, wy0 = 1.0 - wy1;
    double samp[8] = {0, 0, 0, 0, 0, 0, 0, 0};
    const float* cb = child_t + (size_t)b * HW * 64 + ch * 8;
    #pragma unroll
    for (int cy = 0; cy < 2; ++cy) {
        double yq = y0 + (double)cy;
        bool vy = (yq >= 0.0) && (yq <= 31.0);
        double wy = cy ? wy1 : wy0;
        #pragma unroll
        for (int cx = 0; cx < 2; ++cx) {
            double xq = x0 + (double)cx;
            bool ok = vy && (xq >= 0.0) && (xq <= 31.0);
            if (!ok) continue;
            int yi = (int)yq, xi = (int)xq;
            double w = wy * (cx ? wx1 : wx0);
            const float* cp = cb + (size_t)(yi * Wd + xi) * 64;
            #pragma unroll
            for (int i = 0; i < 8; ++i) samp[i] += w * (double)cp[i];
        }
    }
    float sf[8];
    #pragma unroll
    for (int i = 0; i < 8; ++i) sf[i] = (float)samp[i];

    // ---- u_hat = W[n] . samp  (coalesced float4 weight loads) ----
    float u[4][16];
    const float4* wt4 = reinterpret_cast<const float4*>(wt) + lane;
    #pragma unroll
    for (int j4 = 0; j4 < 128; ++j4) {
        float4 wv = wt4[(size_t)j4 * 64];
        int o_loc = j4 >> 5, d = (j4 >> 1) & 15, i4 = (j4 & 1) * 4;
        float val = wv.x * sf[i4] + wv.y * sf[i4 + 1] +
                    wv.z * sf[i4 + 2] + wv.w * sf[i4 + 3];
        if ((j4 & 1) == 0) u[o_loc][d] = val; else u[o_loc][d] += val;
    }

    // ---- dynamic routing (3 iters) ----
    float bl[4] = {0.f, 0.f, 0.f, 0.f};
    float vv[4][16];
    #pragma unroll
    for (int it = 0; it < 3; ++it) {
        // softmax over 8 parents: local 4 + lane pair (xor 1)
        float mx = fmaxf(fmaxf(bl[0], bl[1]), fmaxf(bl[2], bl[3]));
        mx = fmaxf(mx, __shfl_xor(mx, 1));
        float ex[4], ssum = 0.f;
        #pragma unroll
        for (int k = 0; k < 4; ++k) { ex[k] = expf(bl[k] - mx); ssum += ex[k]; }
        ssum += __shfl_xor(ssum, 1);
        float c[4];
        #pragma unroll
        for (int k = 0; k < 4; ++k) c[k] = ex[k] / ssum;
        // partial s then butterfly all-reduce over n (lanes stride 2)
        #pragma unroll
        for (int o = 0; o < 4; ++o)
            #pragma unroll
            for (int d = 0; d < 16; ++d) vv[o][d] = c[o] * u[o][d];
        #pragma unroll
        for (int mk = 2; mk <= 32; mk <<= 1)
            #pragma unroll
            for (int o = 0; o < 4; ++o)
                #pragma unroll
                for (int d = 0; d < 16; ++d)
                    vv[o][d] += __shfl_xor(vv[o][d], mk);
        // squash per parent (fully lane-local)
        #pragma unroll
        for (int o = 0; o < 4; ++o) {
            float sq = 0.f;
            #pragma unroll
            for (int d = 0; d < 16; ++d) sq += vv[o][d] * vv[o][d];
            float f = (sq / (1.f + sq)) / sqrtf(sq + 1e-7f);
            #pragma unroll
            for (int d = 0; d < 16; ++d) vv[o][d] *= f;
        }
        if (it < 2) {  // agreement update (lane-local)
            #pragma unroll
            for (int o = 0; o < 4; ++o) {
                float agg = 0.f;
                #pragma unroll
                for (int d = 0; d < 16; ++d) agg += u[o][d] * vv[o][d];
                bl[o] += agg;
            }
        }
    }

    // ---- scatter v to out[b][ (half*4+o_loc)*16 + d ][hw] ----
    int o_loc = n >> 3;
    int och = half * 4 + o_loc;
    #pragma unroll
    for (int e = 0; e < 2; ++e) {
        int d = (n & 7) * 2 + e;
        out[((size_t)b * 128 + och * 16 + d) * HW + hw] = vv[o_loc][d];
    }
}

extern "C" void kernel_launch(void* const* d_in, const int* in_sizes, int n_in,
                              void* d_out, int out_size, void* d_ws, size_t ws_size,
                              hipStream_t stream) {
    const float* x     = (const float*)d_in[0];
    const float* pw    = (const float*)d_in[1];
    const float* gamma = (const float*)d_in[2];
    const float* beta  = (const float*)d_in[3];
    const float* mean  = (const float*)d_in[4];
    const float* var   = (const float*)d_in[5];
    const float* ow    = (const float*)d_in[6];
    const float* ob    = (const float*)d_in[7];
    const float* rw    = (const float*)d_in[8];
    float* out = (float*)d_out;
    char* ws = (char*)d_ws;
    float* child_t = (float*)ws;                    // 8192*64*4 = 2 MiB
    float* grids   = (float*)(ws + 2097152);        // 8192*8*4  = 256 KiB
    float* wt      = (float*)(ws + 2359296);        // 32768*4   = 128 KiB

    hipLaunchKernelGGL(kA, dim3(2048), dim3(256), 0, stream,
                       x, pw, gamma, beta, mean, var, child_t);
    hipLaunchKernelGGL(kB, dim3(256), dim3(256), 0, stream, x, ow, ob, grids);
    hipLaunchKernelGGL(kC, dim3(128), dim3(256), 0, stream, rw, wt);
    hipLaunchKernelGGL(kD, dim3(2048), dim3(256), 0, stream,
                       child_t, grids, wt, out);
}

// Round 2
// 228.853 us; speedup vs baseline: 2.0748x; 2.0748x over previous
//
#include <hip/hip_runtime.h>
#include <math.h>

#define HW 1024
#define Hd 32
#define Wd 32
#define Bn 8
#define Cc 256

// ---------------- Kernel A: primary caps (1x1 conv + BN + SiLU + squash) ----
// one wave per pixel; lane = output channel (64). child stored [pix][64].
// ALSO emits xt[pix][256] (transposed x) for the offset-conv kernel.
__global__ __launch_bounds__(256) void kA(const float* __restrict__ x,
        const float* __restrict__ pw, const float* __restrict__ gamma,
        const float* __restrict__ beta, const float* __restrict__ mean,
        const float* __restrict__ var, float* __restrict__ child_t,
        float* __restrict__ xt) {
    __shared__ float xs[4][256];
    int wid = threadIdx.x >> 6;
    int lane = threadIdx.x & 63;
    int m = blockIdx.x * 4 + wid;           // pixel 0..8191
    int b = m >> 10, hw = m & 1023;
    const float* xp = x + (size_t)b * Cc * HW + hw;
    #pragma unroll
    for (int k = 0; k < 4; ++k) {
        float v = xp[(size_t)(lane + 64 * k) * HW];
        xs[wid][lane + 64 * k] = v;
        xt[(size_t)m * 256 + lane + 64 * k] = v;   // fused transpose
    }
    __syncthreads();
    int o = lane;
    double acc = 0.0;
    const float4* w4 = reinterpret_cast<const float4*>(pw + o * 256);
    #pragma unroll 16
    for (int c4 = 0; c4 < 64; ++c4) {
        float4 wv = w4[c4];
        acc += (double)wv.x * (double)xs[wid][c4 * 4 + 0];
        acc += (double)wv.y * (double)xs[wid][c4 * 4 + 1];
        acc += (double)wv.z * (double)xs[wid][c4 * 4 + 2];
        acc += (double)wv.w * (double)xs[wid][c4 * 4 + 3];
    }
    double t = (acc - (double)mean[o]) / sqrt((double)var[o] + 1e-5) *
               (double)gamma[o] + (double)beta[o];
    double s = t / (1.0 + exp(-t));              // SiLU
    double sq = s * s;                            // squash over 8-lane capsule
    sq += __shfl_xor(sq, 1);
    sq += __shfl_xor(sq, 2);
    sq += __shfl_xor(sq, 4);
    double f = (sq / (1.0 + sq)) / sqrt(sq + 1e-7);
    child_t[(size_t)m * 64 + o] = (float)(s * f);
}

// ---------------- Kernel C2: transpose conv weights to [tap][oc][c] ---------
__global__ void kC2(const float* __restrict__ ow, float* __restrict__ wt2) {
    int t = blockIdx.x * 256 + threadIdx.x;   // 18432
    int c = t & 255, oc = (t >> 8) & 7, tap = t >> 11;
    wt2[t] = ow[(oc * 256 + c) * 9 + tap];
}

// ---------------- Kernel B: 3x3 offset conv + tanh -> sampling grids --------
// one wave per pixel; lane = 4-channel chunk. weights (taps 0..7) in LDS.
__global__ __launch_bounds__(256) void kB(const float* __restrict__ xt,
        const float* __restrict__ wt2, const float* __restrict__ ob,
        float* __restrict__ grids) {
    __shared__ float wl[16384];               // 8 taps x 8 oc x 256 c = 64 KB
    #pragma unroll
    for (int i = threadIdx.x; i < 4096; i += 256)
        reinterpret_cast<float4*>(wl)[i] =
            reinterpret_cast<const float4*>(wt2)[i];
    __syncthreads();

    int wid = threadIdx.x >> 6, lane = threadIdx.x & 63;
    int m = blockIdx.x * 4 + wid;             // pixel
    int b = m >> 10, hw = m & 1023;
    int yy = hw >> 5, xx = hw & 31;
    const float* xb = xt + (size_t)b * HW * 256;

    float acc[8] = {0.f, 0.f, 0.f, 0.f, 0.f, 0.f, 0.f, 0.f};
    #pragma unroll
    for (int tap = 0; tap < 9; ++tap) {
        int ky = tap / 3 - 1, kx = tap % 3 - 1;
        int yq = yy + ky, xq = xx + kx;
        if (yq < 0 || yq > Hd - 1 || xq < 0 || xq > Wd - 1) continue;
        float4 xv = *reinterpret_cast<const float4*>(
            xb + (size_t)(yq * Wd + xq) * 256 + lane * 4);
        #pragma unroll
        for (int oc = 0; oc < 8; ++oc) {
            float4 wv = (tap < 8)
                ? *reinterpret_cast<const float4*>(wl + (tap * 8 + oc) * 256 + lane * 4)
                : *reinterpret_cast<const float4*>(wt2 + (8 * 8 + oc) * 256 + lane * 4);
            acc[oc] += xv.x * wv.x + xv.y * wv.y + xv.z * wv.z + xv.w * wv.w;
        }
    }
    #pragma unroll
    for (int mk = 1; mk <= 32; mk <<= 1)
        #pragma unroll
        for (int oc = 0; oc < 8; ++oc)
            acc[oc] += __shfl_xor(acc[oc], mk);

    if (lane < 8) {
        double t = tanh((double)acc[lane] + (double)ob[lane]);
        int coord = lane & 1, si = lane >> 1;
        double base = coord ? (-1.0 + 2.0 * (double)yy / 31.0)
                            : (-1.0 + 2.0 * (double)xx / 31.0);
        grids[(size_t)m * 8 + si * 2 + coord] = (float)(base + t / 15.5);
    }
}

// ---------------- Kernel C: reorder routing_W for coalesced float4 reads ----
// lane l <-> (n = l>>1, half = l&1); chunk j = o_loc*128 + d*8 + i (512 floats)
// wt[j4*256 + l*4 + e] = W[n*1024 + half*512 + j4*4 + e]
__global__ void kC(const float* __restrict__ rw, float* __restrict__ wt) {
    int t = blockIdx.x * 256 + threadIdx.x;  // 32768
    int e = t & 3, l = (t >> 2) & 63, j4 = t >> 8;
    int n = l >> 1, half = l & 1;
    wt[t] = rw[n * 1024 + half * 512 + j4 * 4 + e];
}

// ---------------- Kernel D: bilinear sample + u_hat + dynamic routing -------
// one wave per pixel. lane <-> (n = lane>>1, half = lane&1).
// u_hat[n][half*4+o_loc][d] lives in regs u[4][16].
__global__ __launch_bounds__(256) void kD(const float* __restrict__ child_t,
        const float* __restrict__ grids, const float* __restrict__ wt,
        float* __restrict__ out) {
    int wid = threadIdx.x >> 6, lane = threadIdx.x & 63;
    int m = blockIdx.x * 4 + wid;             // pixel
    int b = m >> 10, hw = m & 1023;
    int n = lane >> 1, half = lane & 1;
    int si = n >> 3, ch = n & 7;

    // ---- bilinear sampling (align_corners=True, zeros padding) ----
    float gx = grids[m * 8 + si * 2 + 0];
    float gy = grids[m * 8 + si * 2 + 1];
    double xd = ((double)gx + 1.0) * 0.5 * 31.0;
    double yd = ((double)gy + 1.0) * 0.5 * 31.0;
    double x0 = floor(xd), y0 = floor(yd);
    double wx1 = xd - x0, wx0 = 1.0 - wx1;
    double wy1 = yd - y0, wy0 = 1.0 - wy1;
    double samp[8] = {0, 0, 0, 0, 0, 0, 0, 0};
    const float* cb = child_t + (size_t)b * HW * 64 + ch * 8;
    #pragma unroll
    for (int cy = 0; cy < 2; ++cy) {
        double yq = y0 + (double)cy;
        bool vy = (yq >= 0.0) && (yq <= 31.0);
        double wy = cy ? wy1 : wy0;
        #pragma unroll
        for (int cx = 0; cx < 2; ++cx) {
            double xq = x0 + (double)cx;
            bool ok = vy && (xq >= 0.0) && (xq <= 31.0);
            if (!ok) continue;
            int yi = (int)yq, xi = (int)xq;
            double w = wy * (cx ? wx1 : wx0);
            const float* cp = cb + (size_t)(yi * Wd + xi) * 64;
            #pragma unroll
            for (int i = 0; i < 8; ++i) samp[i] += w * (double)cp[i];
        }
    }
    float sf[8];
    #pragma unroll
    for (int i = 0; i < 8; ++i) sf[i] = (float)samp[i];

    // ---- u_hat = W[n] . samp  (coalesced float4 weight loads) ----
    float u[4][16];
    const float4* wt4 = reinterpret_cast<const float4*>(wt) + lane;
    #pragma unroll
    for (int j4 = 0; j4 < 128; ++j4) {
        float4 wv = wt4[(size_t)j4 * 64];
        int o_loc = j4 >> 5, d = (j4 >> 1) & 15, i4 = (j4 & 1) * 4;
        float val = wv.x * sf[i4] + wv.y * sf[i4 + 1] +
                    wv.z * sf[i4 + 2] + wv.w * sf[i4 + 3];
        if ((j4 & 1) == 0) u[o_loc][d] = val; else u[o_loc][d] += val;
    }

    // ---- dynamic routing (3 iters) ----
    float bl[4] = {0.f, 0.f, 0.f, 0.f};
    float vv[4][16];
    #pragma unroll
    for (int it = 0; it < 3; ++it) {
        // softmax over 8 parents: local 4 + lane pair (xor 1)
        float mx = fmaxf(fmaxf(bl[0], bl[1]), fmaxf(bl[2], bl[3]));
        mx = fmaxf(mx, __shfl_xor(mx, 1));
        float ex[4], ssum = 0.f;
        #pragma unroll
        for (int k = 0; k < 4; ++k) { ex[k] = expf(bl[k] - mx); ssum += ex[k]; }
        ssum += __shfl_xor(ssum, 1);
        float c[4];
        #pragma unroll
        for (int k = 0; k < 4; ++k) c[k] = ex[k] / ssum;
        // partial s then butterfly all-reduce over n (lanes stride 2)
        #pragma unroll
        for (int o = 0; o < 4; ++o)
            #pragma unroll
            for (int d = 0; d < 16; ++d) vv[o][d] = c[o] * u[o][d];
        #pragma unroll
        for (int mk = 2; mk <= 32; mk <<= 1)
            #pragma unroll
            for (int o = 0; o < 4; ++o)
                #pragma unroll
                for (int d = 0; d < 16; ++d)
                    vv[o][d] += __shfl_xor(vv[o][d], mk);
        // squash per parent (fully lane-local)
        #pragma unroll
        for (int o = 0; o < 4; ++o) {
            float sq = 0.f;
            #pragma unroll
            for (int d = 0; d < 16; ++d) sq += vv[o][d] * vv[o][d];
            float f = (sq / (1.f + sq)) / sqrtf(sq + 1e-7f);
            #pragma unroll
            for (int d = 0; d < 16; ++d) vv[o][d] *= f;
        }
        if (it < 2) {  // agreement update (lane-local)
            #pragma unroll
            for (int o = 0; o < 4; ++o) {
                float agg = 0.f;
                #pragma unroll
                for (int d = 0; d < 16; ++d) agg += u[o][d] * vv[o][d];
                bl[o] += agg;
            }
        }
    }

    // ---- scatter v to out[b][ (half*4+o_loc)*16 + d ][hw] ----
    int o_loc = n >> 3;
    int och = half * 4 + o_loc;
    #pragma unroll
    for (int e = 0; e < 2; ++e) {
        int d = (n & 7) * 2 + e;
        out[((size_t)b * 128 + och * 16 + d) * HW + hw] = vv[o_loc][d];
    }
}

extern "C" void kernel_launch(void* const* d_in, const int* in_sizes, int n_in,
                              void* d_out, int out_size, void* d_ws, size_t ws_size,
                              hipStream_t stream) {
    const float* x     = (const float*)d_in[0];
    const float* pw    = (const float*)d_in[1];
    const float* gamma = (const float*)d_in[2];
    const float* beta  = (const float*)d_in[3];
    const float* mean  = (const float*)d_in[4];
    const float* var   = (const float*)d_in[5];
    const float* ow    = (const float*)d_in[6];
    const float* ob    = (const float*)d_in[7];
    const float* rw    = (const float*)d_in[8];
    float* out = (float*)d_out;
    char* ws = (char*)d_ws;
    float* child_t = (float*)ws;                    // 8192*64*4 = 2 MiB
    float* grids   = (float*)(ws + 2097152);        // 8192*8*4  = 256 KiB
    float* wt      = (float*)(ws + 2359296);        // 32768*4   = 128 KiB
    float* xt      = (float*)(ws + 2490368);        // 8192*256*4 = 8 MiB
    float* wt2     = (float*)(ws + 10878976);       // 18432*4   = 72 KiB

    hipLaunchKernelGGL(kA, dim3(2048), dim3(256), 0, stream,
                       x, pw, gamma, beta, mean, var, child_t, xt);
    hipLaunchKernelGGL(kC2, dim3(72), dim3(256), 0, stream, ow, wt2);
    hipLaunchKernelGGL(kB, dim3(2048), dim3(256), 0, stream, xt, wt2, ob, grids);
    hipLaunchKernelGGL(kC, dim3(128), dim3(256), 0, stream, rw, wt);
    hipLaunchKernelGGL(kD, dim3(2048), dim3(256), 0, stream,
                       child_t, grids, wt, out);
}